// Round 1
// baseline (350.842 us; speedup 1.0000x reference)
//
#include <hip/hip_runtime.h>

// ConstGCN collapse:
//   p = softmax(s[:, :, None] + mask, axis=2)  ->  p.sum(axis=2) == 1 exactly,
//   so out = relu(text + emb @ fc_W^T + fc_b), emb = mean_k emb_table[labels].
//   Mean commutes with the linear map -> precompute per-label projected rows:
//   ptab[n][d] = 0.125 * (dot(emb_table[n], fc_W[d]) + fc_b[d])   [100 x 256]
//   out[p][d]  = relu(text[p][d] + sum_{k<8} ptab[label_k][d])
// const_mat (256 MiB), attn_W, attn_b are dead inputs — never read.

constexpr int D  = 256;   // text feature dim
constexpr int CD = 128;   // const embedding dim
constexpr int K  = 8;     // labels per position

__global__ __launch_bounds__(256) void build_ptab(
    const float* __restrict__ emb_table,   // [CN, CD]
    const float* __restrict__ fc_W,        // [D, CD] row-major
    const float* __restrict__ fc_b,        // [D]
    float* __restrict__ ptab)              // [CN, D]
{
    const int n = blockIdx.x;    // const-label id
    const int d = threadIdx.x;   // output feature
    const float4* er = reinterpret_cast<const float4*>(emb_table + n * CD);
    const float4* wr = reinterpret_cast<const float4*>(fc_W + d * CD);
    float acc = 0.0f;
#pragma unroll
    for (int c = 0; c < CD / 4; ++c) {
        const float4 e = er[c];
        const float4 w = wr[c];
        acc += e.x * w.x;
        acc += e.y * w.y;
        acc += e.z * w.z;
        acc += e.w * w.w;
    }
    ptab[n * D + d] = 0.125f * (acc + fc_b[d]);
}

// One wave (64 lanes) per position; each lane handles 4 contiguous floats
// (float4). Table-row gathers are wave-coalesced 1 KB reads from a 100 KB
// table (L2-resident). Labels are lane-uniform -> readfirstlane so row base
// addresses become SGPRs.
__global__ __launch_bounds__(256) void fused_out(
    const float* __restrict__ text,    // [npos, D]
    const int*   __restrict__ labels,  // [npos, K]
    const float* __restrict__ ptab,    // [CN, D]
    float* __restrict__ out,           // [npos, D]
    int npos)
{
    const int lane = threadIdx.x & 63;
    const int pos  = (int)((blockIdx.x * blockDim.x + threadIdx.x) >> 6);
    if (pos >= npos) return;

    const int* lab = labels + (size_t)pos * K;
    int n[K];
#pragma unroll
    for (int k = 0; k < K; ++k)
        n[k] = __builtin_amdgcn_readfirstlane(lab[k]);

    float4 acc = make_float4(0.f, 0.f, 0.f, 0.f);
#pragma unroll
    for (int k = 0; k < K; ++k) {
        const float4 v =
            reinterpret_cast<const float4*>(ptab + (size_t)n[k] * D)[lane];
        acc.x += v.x; acc.y += v.y; acc.z += v.z; acc.w += v.w;
    }

    const float4 t = reinterpret_cast<const float4*>(text + (size_t)pos * D)[lane];
    float4 o;
    o.x = fmaxf(t.x + acc.x, 0.0f);
    o.y = fmaxf(t.y + acc.y, 0.0f);
    o.z = fmaxf(t.z + acc.z, 0.0f);
    o.w = fmaxf(t.w + acc.w, 0.0f);
    reinterpret_cast<float4*>(out + (size_t)pos * D)[lane] = o;
}

extern "C" void kernel_launch(void* const* d_in, const int* in_sizes, int n_in,
                              void* d_out, int out_size, void* d_ws, size_t ws_size,
                              hipStream_t stream)
{
    const float* text      = (const float*)d_in[0];
    // d_in[1] const_mat: UNUSED (softmax over j sums to 1 for any mask)
    const int*   labels    = (const int*)d_in[2];
    const float* emb_table = (const float*)d_in[3];
    // d_in[4] attn_W, d_in[5] attn_b: UNUSED (only feed s, which cancels)
    const float* fc_W      = (const float*)d_in[6];
    const float* fc_b      = (const float*)d_in[7];
    float* out  = (float*)d_out;
    float* ptab = (float*)d_ws;             // [CN, D] = CN*256 floats (100 KB)

    const int CN   = in_sizes[3] / CD;      // 100
    const int npos = in_sizes[0] / D;       // B*L = 32768

    build_ptab<<<CN, D, 0, stream>>>(emb_table, fc_W, fc_b, ptab);

    const int waves_per_block = 4;          // 256 threads / 64
    const int nblocks = (npos + waves_per_block - 1) / waves_per_block;
    fused_out<<<nblocks, 256, 0, stream>>>(text, labels, ptab, out, npos);
}

// Round 3
// 348.062 us; speedup vs baseline: 1.0080x; 1.0080x over previous
//
#include <hip/hip_runtime.h>

// ConstGCN collapse (verified R0, absmax 1.6e-2 vs threshold 1.05e-1):
//   p = softmax(s[:, :, None] + mask, axis=2)  ->  p.sum(axis=2) == 1 exactly,
//   so out = relu(text + emb @ fc_W^T + fc_b), emb = mean_k emb_table[labels].
//   Mean commutes with the linear map -> precompute per-label projected rows:
//   ptab[n][d] = 0.125 * (dot(emb_table[n], fc_W[d]) + fc_b[d])   [100 x 256]
//   out[p][d]  = relu(text[p][d] + sum_{k<8} ptab[label_k][d])
// const_mat (256 MiB), attn_W, attn_b are dead inputs — never read.
//
// R1 evidence: dur_us (350 us) dominated by harness per-iteration
// restore/poison (1 GiB ws fill + 256 MiB const_mat restore at 84% HBM peak,
// ~265-330 us fixed; top-5 dispatches were all fillBufferAligned). Kernel-side
// floor ~12-14 us. R2 fix: nontemporal builtins need clang ext_vector_type,
// not HIP_vector_type.

constexpr int D  = 256;   // text feature dim
constexpr int CD = 128;   // const embedding dim
constexpr int K  = 8;     // labels per position

typedef float vf4 __attribute__((ext_vector_type(4)));
typedef int   vi4 __attribute__((ext_vector_type(4)));

__global__ __launch_bounds__(256) void build_ptab(
    const float* __restrict__ emb_table,   // [CN, CD]
    const float* __restrict__ fc_W,        // [D, CD] row-major
    const float* __restrict__ fc_b,        // [D]
    float* __restrict__ ptab)              // [CN, D]
{
    const int n = blockIdx.x;    // const-label id
    const int d = threadIdx.x;   // output feature
    const vf4* er = reinterpret_cast<const vf4*>(emb_table + n * CD);
    const vf4* wr = reinterpret_cast<const vf4*>(fc_W + d * CD);
    float acc = 0.0f;
#pragma unroll
    for (int c = 0; c < CD / 4; ++c) {
        const vf4 e = er[c];
        const vf4 w = wr[c];
        acc += e.x * w.x;
        acc += e.y * w.y;
        acc += e.z * w.z;
        acc += e.w * w.w;
    }
    ptab[n * D + d] = 0.125f * (acc + fc_b[d]);
}

// One wave (64 lanes) per position; lane handles 4 contiguous floats (vf4):
// text/out are wave-coalesced 1 KB transactions, nontemporal (single-use
// stream) so TCC capacity/BW serves the L2-resident ptab gathers. Labels
// loaded as two 16B vi4 (wave-uniform address), readfirstlane -> scalar row
// bases for the 8 ptab row gathers (100 KB table).
__global__ __launch_bounds__(256) void fused_out(
    const float* __restrict__ text,    // [npos, D]
    const int*   __restrict__ labels,  // [npos, K]
    const float* __restrict__ ptab,    // [CN, D]
    float* __restrict__ out,           // [npos, D]
    int npos)
{
    const int lane = threadIdx.x & 63;
    const int pos  = (int)((blockIdx.x * blockDim.x + threadIdx.x) >> 6);
    if (pos >= npos) return;

    // Kick off the streaming text load first (nontemporal: single-use data).
    const vf4* trow = reinterpret_cast<const vf4*>(text + (size_t)pos * D);
    const vf4 t = __builtin_nontemporal_load(&trow[lane]);

    // 8 labels as two 16B loads (wave-uniform addresses -> broadcast).
    const vi4* lab4 = reinterpret_cast<const vi4*>(labels + (size_t)pos * K);
    const vi4 la = lab4[0];
    const vi4 lb = lab4[1];
    int n[K];
    n[0] = __builtin_amdgcn_readfirstlane(la.x);
    n[1] = __builtin_amdgcn_readfirstlane(la.y);
    n[2] = __builtin_amdgcn_readfirstlane(la.z);
    n[3] = __builtin_amdgcn_readfirstlane(la.w);
    n[4] = __builtin_amdgcn_readfirstlane(lb.x);
    n[5] = __builtin_amdgcn_readfirstlane(lb.y);
    n[6] = __builtin_amdgcn_readfirstlane(lb.z);
    n[7] = __builtin_amdgcn_readfirstlane(lb.w);

    // Issue all 8 independent row gathers before reducing (MLP: 8 in flight).
    vf4 v[K];
#pragma unroll
    for (int k = 0; k < K; ++k)
        v[k] = reinterpret_cast<const vf4*>(ptab + (size_t)n[k] * D)[lane];

    vf4 acc = v[0] + v[1];
#pragma unroll
    for (int k = 2; k < K; ++k) acc += v[k];

    vf4 o;
    o.x = fmaxf(t.x + acc.x, 0.0f);
    o.y = fmaxf(t.y + acc.y, 0.0f);
    o.z = fmaxf(t.z + acc.z, 0.0f);
    o.w = fmaxf(t.w + acc.w, 0.0f);
    vf4* orow = reinterpret_cast<vf4*>(out + (size_t)pos * D);
    __builtin_nontemporal_store(o, &orow[lane]);
}

extern "C" void kernel_launch(void* const* d_in, const int* in_sizes, int n_in,
                              void* d_out, int out_size, void* d_ws, size_t ws_size,
                              hipStream_t stream)
{
    const float* text      = (const float*)d_in[0];
    // d_in[1] const_mat: UNUSED (softmax over j sums to 1 for any mask)
    const int*   labels    = (const int*)d_in[2];
    const float* emb_table = (const float*)d_in[3];
    // d_in[4] attn_W, d_in[5] attn_b: UNUSED (only feed s, which cancels)
    const float* fc_W      = (const float*)d_in[6];
    const float* fc_b      = (const float*)d_in[7];
    float* out  = (float*)d_out;
    float* ptab = (float*)d_ws;             // [CN, D] = CN*256 floats (100 KB)

    const int CN   = in_sizes[3] / CD;      // 100
    const int npos = in_sizes[0] / D;       // B*L = 32768

    build_ptab<<<CN, D, 0, stream>>>(emb_table, fc_W, fc_b, ptab);

    const int waves_per_block = 4;          // 256 threads / 64
    const int nblocks = (npos + waves_per_block - 1) / waves_per_block;
    fused_out<<<nblocks, 256, 0, stream>>>(text, labels, ptab, out, npos);
}